// Round 5
// baseline (66.674 us; speedup 1.0000x reference)
//
#include <hip/hip_runtime.h>

// 5-level wavedec (filter len 8, pywt 'symmetric'), 4096 rows of 8192 f32.
// Lengths: 8192 -> 4099 -> 2053 -> 1030 -> 518 -> 262
// Out: approx(262) @0, d5(262), d4(518), d3(1030), d2(2053), d1(4099).
// Interior: 4 outputs/thread from 5x float4 loads (base 8j-8, 16B-aligned),
// 64 FMA, one 16B store per filter. Linear LDS layout (no padding).

static constexpr int ROWS = 4096;
static constexpr int N0 = 8192;
static constexpr int L1n = 4099, L2n = 2053, L3n = 1030, L4n = 518, L5n = 262;
static constexpr size_t OFF_D5 = 1073152u;
static constexpr size_t OFF_D4 = 2146304u;
static constexpr size_t OFF_D3 = 4268032u;
static constexpr size_t OFF_D2 = 8486912u;
static constexpr size_t OFF_D1 = 16896000u;

typedef float f4 __attribute__((ext_vector_type(4)));
typedef f4 f4a __attribute__((aligned(4)));   // 4B-aligned vector for odd-based global rows

template <bool LAST>
__device__ __forceinline__ void dwt_level(
    const float* __restrict__ src, int n, int m,
    const float* __restrict__ h, const float* __restrict__ g,
    float* __restrict__ adst, float* __restrict__ ddst, int tid)
{
    const int ngroups = (m + 3) >> 2;
    const int jmax = (n - 12) >> 3;   // interior iff 1 <= j <= jmax (needs 8j+11 <= n-1)
    for (int j = tid; j < ngroups; j += 256) {
        const int p0 = 4 * j;
        if (j >= 1 && j <= jmax && p0 + 3 < m) {
            // load floats [8j-8 .. 8j+11] as 5x float4 (16B-aligned)
            const f4* __restrict__ s4 = reinterpret_cast<const f4*>(src + (8 * j - 8));
            f4 vv[5];
#pragma unroll
            for (int t = 0; t < 5; ++t) vv[t] = s4[t];
            float W[20];
#pragma unroll
            for (int i = 0; i < 20; ++i) W[i] = vv[i >> 2][i & 3];
            f4 aa, dd;
#pragma unroll
            for (int r = 0; r < 4; ++r) {
                float a = 0.f, d = 0.f;
#pragma unroll
                for (int q = 0; q < 8; ++q) {
                    const float v = W[2 * r + 9 - q];   // src[2(p0+r)+1-q]
                    a = fmaf(h[q], v, a);
                    d = fmaf(g[q], v, d);
                }
                aa[r] = a; dd[r] = d;
            }
            *reinterpret_cast<f4a*>(ddst + p0) = dd;       // global, 4B-aligned ok
            if (LAST) *reinterpret_cast<f4a*>(adst + p0) = aa;  // global
            else      *reinterpret_cast<f4*>(adst + p0) = aa;   // LDS, 16B-aligned
        } else {
            // edge groups: branchy symmetric-reflect path (2-3 per level)
#pragma unroll 4
            for (int r = 0; r < 4; ++r) {
                const int pos = p0 + r;
                if (pos >= m) break;
                const int s0 = 2 * pos + 1;
                float a = 0.f, d = 0.f;
#pragma unroll
                for (int q = 0; q < 8; ++q) {
                    int s = s0 - q;
                    int idx = (s < 0) ? (-1 - s) : ((s >= n) ? (2 * n - 1 - s) : s);
                    const float v = src[idx];
                    a = fmaf(h[q], v, a);
                    d = fmaf(g[q], v, d);
                }
                ddst[pos] = d;
                adst[pos] = a;
            }
        }
    }
}

__global__ __launch_bounds__(256, 6)
void wavedec5_kernel(const float* __restrict__ x,
                     const float* __restrict__ dlo,
                     const float* __restrict__ dhi,
                     float* __restrict__ out)
{
    __shared__ __align__(16) float bufA[4100];  // a1 / a3
    __shared__ __align__(16) float bufB[2056];  // a2 / a4

    const int row = blockIdx.x;
    const int tid = threadIdx.x;

    float h[8], g[8];
#pragma unroll
    for (int i = 0; i < 8; ++i) { h[i] = dlo[i]; g[i] = dhi[i]; }

    const float* __restrict__ xr = x + (size_t)row * N0;

    // L1: global -> bufA, d1 -> global
    dwt_level<false>(xr, N0, L1n, h, g, bufA,
                     out + OFF_D1 + (size_t)row * L1n, tid);
    __syncthreads();
    // L2: bufA -> bufB, d2 -> global
    dwt_level<false>(bufA, L1n, L2n, h, g, bufB,
                     out + OFF_D2 + (size_t)row * L2n, tid);
    __syncthreads();
    // L3: bufB -> bufA, d3 -> global
    dwt_level<false>(bufB, L2n, L3n, h, g, bufA,
                     out + OFF_D3 + (size_t)row * L3n, tid);
    __syncthreads();
    // L4: bufA -> bufB, d4 -> global
    dwt_level<false>(bufA, L3n, L4n, h, g, bufB,
                     out + OFF_D4 + (size_t)row * L4n, tid);
    __syncthreads();
    // L5: bufB -> approx & d5 straight to global
    dwt_level<true>(bufB, L4n, L5n, h, g,
                    out + (size_t)row * L5n,
                    out + OFF_D5 + (size_t)row * L5n, tid);
}

extern "C" void kernel_launch(void* const* d_in, const int* in_sizes, int n_in,
                              void* d_out, int out_size, void* d_ws, size_t ws_size,
                              hipStream_t stream) {
    const float* x   = (const float*)d_in[0];
    const float* dlo = (const float*)d_in[1];
    const float* dhi = (const float*)d_in[2];
    float* out = (float*)d_out;
    wavedec5_kernel<<<ROWS, 256, 0, stream>>>(x, dlo, dhi, out);
}